// Round 3
// baseline (156.108 us; speedup 1.0000x reference)
//
#include <hip/hip_runtime.h>
#include <stdint.h>

#pragma clang fp contract(off)

#define NB 128
#define NC 12
#define NTT 5000
#define BLK 256

typedef unsigned int u32;

// Canonical Threefry-2x32, 20 rounds (matches JAX / Random123).
__device__ __forceinline__ void tf2(u32 k0, u32 k1, u32 c0, u32 c1, u32& o0, u32& o1) {
  u32 k2 = k0 ^ k1 ^ 0x1BD11BDAu;
  u32 x0 = c0 + k0, x1 = c1 + k1;
#define TFR(r) x0 += x1; x1 = (x1 << (r)) | (x1 >> (32 - (r))); x1 ^= x0;
  TFR(13) TFR(15) TFR(26) TFR(6)
  x0 += k1; x1 += k2 + 1u;
  TFR(17) TFR(29) TFR(16) TFR(24)
  x0 += k2; x1 += k0 + 2u;
  TFR(13) TFR(15) TFR(26) TFR(6)
  x0 += k0; x1 += k1 + 3u;
  TFR(17) TFR(29) TFR(16) TFR(24)
  x0 += k1; x1 += k2 + 4u;
  TFR(13) TFR(15) TFR(26) TFR(6)
  x0 += k2; x1 += k0 + 5u;
#undef TFR
  o0 = x0; o1 = x1;
}

// JAX f32 uniform bit->float: [1,2) - 1. Partitionable 32-bit bits = o0^o1.
__device__ __forceinline__ float u01(u32 bits) {
  return __uint_as_float((bits >> 9) | 0x3F800000u) - 1.0f;
}

// XLA ErfInv32 (Giles), matches jax.lax.erf_inv f32 lowering.
__device__ __forceinline__ float erfinv_xla(float x) {
  float xx = x * x;
  float w = -log1pf(-xx);
  float p;
  if (w < 5.0f) {
    w = w - 2.5f;
    p = 2.81022636e-08f;
    p = 3.43273939e-07f + p * w;
    p = -3.5233877e-06f + p * w;
    p = -4.39150654e-06f + p * w;
    p = 0.00021858087f + p * w;
    p = -0.00125372503f + p * w;
    p = -0.00417768164f + p * w;
    p = 0.246640727f + p * w;
    p = 1.50140941f + p * w;
  } else {
    w = sqrtf(w) - 3.0f;
    p = -0.000200214257f;
    p = 0.000100950558f + p * w;
    p = 0.00134934322f + p * w;
    p = -0.00367342844f + p * w;
    p = 0.00573950773f + p * w;
    p = -0.0076224613f + p * w;
    p = 0.00943887047f + p * w;
    p = 1.00167406f + p * w;
    p = 2.83297682f + p * w;
  }
  return p * x;
}

struct SSc {
  float w[7];
  float mag0, scale1, mag3, amp4, freq, ph, wf, wp;
  int start, end_, shift;
  u32 nk0, nk1;
};

__global__ __launch_bounds__(BLK) void aug_fused(
    const float* __restrict__ xin, const float* __restrict__ logits,
    const float* __restrict__ mag_neg, const float* __restrict__ mag_pos,
    const int* __restrict__ labels, float* __restrict__ xout) {
  __shared__ float rowA[NTT];
  __shared__ float rowB[NTT];
  __shared__ SSc ssc[2];

  const int bc = blockIdx.x;
  const int b = bc / NC;
  const int rowbase = bc * NTT;
  const int tid = threadIdx.x;

  // Stage input row -> LDS
  for (int i = tid; i < NTT; i += BLK) rowA[i] = xin[rowbase + i];

  // Thread 0 derives both stages' scalars (keys, weights, per-b params).
  if (tid == 0) {
    // Label dtype probe (insurance): int64 labels would have all odd 32-bit
    // words zero. Probe first 128 words (valid under both layouts).
    int mode64 = 1;
    for (int i = 1; i < 128; i += 2) {
      if (labels[i] != 0) { mode64 = 0; break; }
    }
    const int lab = mode64 ? labels[2 * b] : labels[b];
    const float lf = (float)lab;

    for (int s = 0; s < 2; ++s) {
      u32 kk0, kk1;
      tf2(0u, 42u, 0u, (u32)s, kk0, kk1);            // fold_in(key(42), s): both words
      u32 ka[7], kb[7];
      for (int j = 0; j < 7; ++j) tf2(kk0, kk1, 0u, (u32)j, ka[j], kb[j]);  // foldlike split

      // gumbel-softmax weights: bits = o0 ^ o1 (partitionable 32-bit draw)
      float v[7];
      for (int j = 0; j < 7; ++j) {
        u32 o0, o1;
        tf2(ka[0], kb[0], 0u, (u32)j, o0, o1);
        float u = fmaxf(u01(o0 ^ o1), 1e-20f);
        float g = -logf(-logf(u));
        v[j] = logits[s * 7 + j] + g;
      }
      float m = v[0];
      for (int j = 1; j < 7; ++j) m = fmaxf(m, v[j]);
      float e[7];
      float sum = 0.0f;
      for (int j = 0; j < 7; ++j) e[j] = expf(v[j] - m);
      for (int j = 0; j < 7; ++j) sum += e[j];
      for (int j = 0; j < 7; ++j) ssc[s].w[j] = e[j] / sum;

      // per-sample magnitudes: |mag_neg + lf*(mag_pos - mag_neg)|  (f32; lf is 0/1)
      float mg[7];
      for (int j = 0; j < 7; ++j) {
        float mn = mag_neg[s * 7 + j];
        float mp = mag_pos[s * 7 + j];
        float d = mp - mn;
        float pr = lf * d;
        mg[j] = fabsf(mn + pr);
      }
      ssc[s].mag0 = mg[0];
      ssc[s].scale1 = 1.0f + mg[1];
      ssc[s].mag3 = mg[3];
      ssc[s].amp4 = 0.1f * mg[4];

      // op2: time mask
      int ml = (int)floorf(mg[2] * 5000.0f);
      ml = ml < 0 ? 0 : (ml > NTT ? NTT : ml);
      u32 o0, o1;
      tf2(ka[2], kb[2], 0u, (u32)b, o0, o1);
      int tml = NTT - ml + 1;
      if (tml < 1) tml = 1;
      int st = (int)floorf(u01(o0 ^ o1) * (float)tml);
      ssc[s].start = st;
      ssc[s].end_ = st + ml;

      // op3: wander params
      tf2(ka[3], kb[3], 0u, (u32)b, o0, o1);
      { float f = u01(o0 ^ o1); float fp = f * 0.3f; ssc[s].freq = fp + 0.05f; }
      tf2(ka[4], kb[4], 0u, (u32)b, o0, o1);
      ssc[s].ph = u01(o0 ^ o1) * 6.283185307179586f;

      // op4: warp params
      tf2(ka[5], kb[5], 0u, (u32)b, o0, o1);
      { float f = u01(o0 ^ o1); float fp = f * 2.0f; ssc[s].wf = fp + 1.0f; }
      tf2(ka[6], kb[6], 0u, (u32)b, o0, o1);
      ssc[s].wp = u01(o0 ^ o1) * 6.283185307179586f;

      // op5: circular shift
      ssc[s].shift = (int)floorf(mg[5] * 5000.0f);

      // noise key (ks[1])
      ssc[s].nk0 = ka[1];
      ssc[s].nk1 = kb[1];
    }
  }
  __syncthreads();

  const float D_T2PI = 6.283185307179586f / 4999.0f;  // linspace(0, 2pi, T) step, f32
  const float D_BASE = 2.0f / 4999.0f;                // linspace(-1, 1, T) step, f32
  const float NLO = -0.9999999403953552f;             // nextafter(-1, 0)
  const float SQRT2 = 1.4142135623730951f;

  for (int s = 0; s < 2; ++s) {
    const SSc sc = ssc[s];
    const float* rin = (s == 0) ? rowA : rowB;
    for (int t = tid; t < NTT; t += BLK) {
      float tf = (float)t;
      float t2 = tf * D_T2PI;

      // op3 wander
      float a3 = sc.freq * t2;
      a3 = a3 + sc.ph;
      float wander = sinf(a3);

      // op4 warp coords
      float a4 = sc.wf * t2;
      a4 = a4 + sc.wp;
      float disp = sc.amp4 * sinf(a4);
      float posb = tf * D_BASE;
      posb = -1.0f + posb;
      float p = posb + disp;
      p = fminf(1.0f, fmaxf(-1.0f, p));
      float px = (p + 1.0f) * 0.5f;
      px = px * 4999.0f;
      int i0 = (int)floorf(px);
      i0 = i0 < 0 ? 0 : (i0 > NTT - 1 ? NTT - 1 : i0);
      int i1 = i0 + 1;
      if (i1 > NTT - 1) i1 = NTT - 1;
      float fr = px - (float)i0;

      // op5 index
      int rt = t - sc.shift;
      if (rt < 0) rt += NTT;

      float xv = rin[t];
      float xl = rin[i0];
      float xr = rin[i1];
      float xs = rin[rt];

      // op0 gaussian noise: bits = o0^o1 -> uniform(lo,1) -> sqrt2*erfinv
      u32 o0, o1;
      tf2(sc.nk0, sc.nk1, 0u, (u32)(rowbase + t), o0, o1);
      float f = u01(o0 ^ o1);
      float un = f * 2.0f;
      un = un + NLO;
      un = fmaxf(NLO, un);
      float nrm = SQRT2 * erfinv_xla(un);

      float y0 = sc.mag0 * nrm;
      y0 = xv + y0;
      float y1 = xv * sc.scale1;
      float y2 = (t >= sc.start && t < sc.end_) ? 0.0f : xv;
      float y3 = sc.mag3 * wander;
      y3 = xv + y3;
      float omf = 1.0f - fr;
      float y4 = xl * omf;
      float y4b = xr * fr;
      y4 = y4 + y4b;

      float r = sc.w[0] * y0;
      r = r + sc.w[1] * y1;
      r = r + sc.w[2] * y2;
      r = r + sc.w[3] * y3;
      r = r + sc.w[4] * y4;
      r = r + sc.w[5] * xs;
      r = r + sc.w[6] * xv;

      if (s == 0) rowB[t] = r;
      else xout[rowbase + t] = r;
    }
    __syncthreads();
  }
}

extern "C" void kernel_launch(void* const* d_in, const int* in_sizes, int n_in,
                              void* d_out, int out_size, void* d_ws, size_t ws_size,
                              hipStream_t stream) {
  (void)in_sizes; (void)n_in; (void)d_ws; (void)ws_size; (void)out_size;
  const float* x = (const float*)d_in[0];
  const float* logits = (const float*)d_in[1];
  const float* mag_neg = (const float*)d_in[2];
  const float* mag_pos = (const float*)d_in[3];
  const int* labels = (const int*)d_in[4];
  float* out = (float*)d_out;
  hipLaunchKernelGGL(aug_fused, dim3(NB * NC), dim3(BLK), 0, stream,
                     x, logits, mag_neg, mag_pos, labels, out);
}

// Round 4
// 100.888 us; speedup vs baseline: 1.5473x; 1.5473x over previous
//
#include <hip/hip_runtime.h>
#include <stdint.h>

#pragma clang fp contract(off)

#define NB 128
#define NC 12
#define NTT 5000
#define BLK 256

typedef unsigned int u32;

// Canonical Threefry-2x32, 20 rounds (matches JAX / Random123).
__device__ __forceinline__ void tf2(u32 k0, u32 k1, u32 c0, u32 c1, u32& o0, u32& o1) {
  u32 k2 = k0 ^ k1 ^ 0x1BD11BDAu;
  u32 x0 = c0 + k0, x1 = c1 + k1;
#define TFR(r) x0 += x1; x1 = (x1 << (r)) | (x1 >> (32 - (r))); x1 ^= x0;
  TFR(13) TFR(15) TFR(26) TFR(6)
  x0 += k1; x1 += k2 + 1u;
  TFR(17) TFR(29) TFR(16) TFR(24)
  x0 += k2; x1 += k0 + 2u;
  TFR(13) TFR(15) TFR(26) TFR(6)
  x0 += k0; x1 += k1 + 3u;
  TFR(17) TFR(29) TFR(16) TFR(24)
  x0 += k1; x1 += k2 + 4u;
  TFR(13) TFR(15) TFR(26) TFR(6)
  x0 += k2; x1 += k0 + 5u;
#undef TFR
  o0 = x0; o1 = x1;
}

// JAX f32 uniform bit->float: [1,2) - 1. Partitionable 32-bit bits = o0^o1.
__device__ __forceinline__ float u01(u32 bits) {
  return __uint_as_float((bits >> 9) | 0x3F800000u) - 1.0f;
}

// Giles erfinv, hw-log variant. 1-xx is Sterbenz-exact for xx>=0.5 (the only
// region where log matters at scale); abs err in w ~1e-7 -> negligible.
__device__ __forceinline__ float erfinv_fast(float x) {
  float xx = x * x;
  float w = -__logf(1.0f - xx);
  float p;
  if (w < 5.0f) {
    w = w - 2.5f;
    p = fmaf(2.81022636e-08f, w, 3.43273939e-07f);
    p = fmaf(p, w, -3.5233877e-06f);
    p = fmaf(p, w, -4.39150654e-06f);
    p = fmaf(p, w, 0.00021858087f);
    p = fmaf(p, w, -0.00125372503f);
    p = fmaf(p, w, -0.00417768164f);
    p = fmaf(p, w, 0.246640727f);
    p = fmaf(p, w, 1.50140941f);
  } else {
    w = __fsqrt_rn(w) - 3.0f;
    p = fmaf(-0.000200214257f, w, 0.000100950558f);
    p = fmaf(p, w, 0.00134934322f);
    p = fmaf(p, w, -0.00367342844f);
    p = fmaf(p, w, 0.00573950773f);
    p = fmaf(p, w, -0.0076224613f);
    p = fmaf(p, w, 0.00943887047f);
    p = fmaf(p, w, 1.00167406f);
    p = fmaf(p, w, 2.83297682f);
  }
  return p * x;
}

struct SSc {
  float w[7];
  float mag0, scale1, mag3, amp4, freq, ph, wf, wp;
  int start, mlen, shift;
  u32 nk0, nk1;
};

__global__ __launch_bounds__(BLK) void aug_fused(
    const float* __restrict__ xin, const float* __restrict__ logits,
    const float* __restrict__ mag_neg, const float* __restrict__ mag_pos,
    const int* __restrict__ labels, float* __restrict__ xout) {
  __shared__ float rowA[NTT];
  __shared__ float rowB[NTT];
  __shared__ SSc ssc[2];

  const int bc = blockIdx.x;
  const int b = bc / NC;
  const int rowbase = bc * NTT;
  const int tid = threadIdx.x;

  // Stage input row -> LDS
  for (int i = tid; i < NTT; i += BLK) rowA[i] = xin[rowbase + i];

  // Thread 0 derives both stages' scalars. Discrete paths (ml/start/shift)
  // keep the exact f32 op sequence that validated in round 3.
  if (tid == 0) {
    // Label dtype probe (insurance): int64 labels would have all odd 32-bit
    // words zero. Probe first 128 words (valid under both layouts).
    int mode64 = 1;
    for (int i = 1; i < 128; i += 2) {
      if (labels[i] != 0) { mode64 = 0; break; }
    }
    const int lab = mode64 ? labels[2 * b] : labels[b];
    const float lf = (float)lab;

    for (int s = 0; s < 2; ++s) {
      u32 kk0, kk1;
      tf2(0u, 42u, 0u, (u32)s, kk0, kk1);            // fold_in(key(42), s)
      u32 ka[7], kb[7];
      for (int j = 0; j < 7; ++j) tf2(kk0, kk1, 0u, (u32)j, ka[j], kb[j]);  // foldlike split

      // gumbel-softmax weights (continuous -> hw log/exp fine)
      float v[7];
      for (int j = 0; j < 7; ++j) {
        u32 o0, o1;
        tf2(ka[0], kb[0], 0u, (u32)j, o0, o1);
        float u = fmaxf(u01(o0 ^ o1), 1e-20f);
        float g = -__logf(-__logf(u));
        v[j] = logits[s * 7 + j] + g;
      }
      float m = v[0];
      for (int j = 1; j < 7; ++j) m = fmaxf(m, v[j]);
      float e[7];
      float sum = 0.0f;
      for (int j = 0; j < 7; ++j) e[j] = __expf(v[j] - m);
      for (int j = 0; j < 7; ++j) sum += e[j];
      for (int j = 0; j < 7; ++j) ssc[s].w[j] = e[j] / sum;

      // per-sample magnitudes: |mag_neg + lf*(mag_pos - mag_neg)| (exact seq)
      float mg[7];
      for (int j = 0; j < 7; ++j) {
        float mn = mag_neg[s * 7 + j];
        float mp = mag_pos[s * 7 + j];
        float d = mp - mn;
        float pr = lf * d;
        mg[j] = fabsf(mn + pr);
      }
      ssc[s].mag0 = mg[0];
      ssc[s].scale1 = 1.0f + mg[1];
      ssc[s].mag3 = mg[3];
      ssc[s].amp4 = 0.1f * mg[4];

      // op2: time mask (discrete -> exact sequence preserved)
      int ml = (int)floorf(mg[2] * 5000.0f);
      ml = ml < 0 ? 0 : (ml > NTT ? NTT : ml);
      u32 o0, o1;
      tf2(ka[2], kb[2], 0u, (u32)b, o0, o1);
      int tml = NTT - ml + 1;
      if (tml < 1) tml = 1;
      int st = (int)floorf(u01(o0 ^ o1) * (float)tml);
      ssc[s].start = st;
      ssc[s].mlen = ml;

      // op3: wander params
      tf2(ka[3], kb[3], 0u, (u32)b, o0, o1);
      { float f = u01(o0 ^ o1); float fp = f * 0.3f; ssc[s].freq = fp + 0.05f; }
      tf2(ka[4], kb[4], 0u, (u32)b, o0, o1);
      ssc[s].ph = u01(o0 ^ o1) * 6.283185307179586f;

      // op4: warp params
      tf2(ka[5], kb[5], 0u, (u32)b, o0, o1);
      { float f = u01(o0 ^ o1); float fp = f * 2.0f; ssc[s].wf = fp + 1.0f; }
      tf2(ka[6], kb[6], 0u, (u32)b, o0, o1);
      ssc[s].wp = u01(o0 ^ o1) * 6.283185307179586f;

      // op5: circular shift (discrete, exact)
      ssc[s].shift = (int)floorf(mg[5] * 5000.0f);

      // noise key (ks[1])
      ssc[s].nk0 = ka[1];
      ssc[s].nk1 = kb[1];
    }
  }
  __syncthreads();

  const float D_T2PI = 6.283185307179586f / 4999.0f;  // linspace(0,2pi,T) step
  const float D_BASE = 2.0f / 4999.0f;                // linspace(-1,1,T) step
  const float NLO = -0.9999999403953552f;             // nextafter(-1, 0)
  const float SQRT2 = 1.4142135623730951f;

  for (int s = 0; s < 2; ++s) {
    const SSc sc = ssc[s];
    const float* rin = (s == 0) ? rowA : rowB;
    // combined mix coefficients:
    // r = xv*(w0 + w1*scale1 + w3 + w6 [+ w2 if unmasked])
    //   + (w0*mag0)*nrm + (w3*mag3)*sin3 + w4*y4 + w5*xs
    const float cc_m = ((sc.w[0] + sc.w[1] * sc.scale1) + sc.w[3]) + sc.w[6];
    const float cc_u = cc_m + sc.w[2];
    const float A0 = sc.w[0] * sc.mag0;
    const float A3 = sc.w[3] * sc.mag3;
    const float W4 = sc.w[4], W5 = sc.w[5];
    const u32 mstart = (u32)sc.start, mlen = (u32)sc.mlen;

    for (int t = tid; t < NTT; t += BLK) {
      float tf = (float)t;
      float t2 = tf * D_T2PI;

      // op3 wander + op4 warp sin (hw sin; args in [0, ~25.2] rad)
      float sin3 = __sinf(fmaf(sc.freq, t2, sc.ph));
      float sin4 = __sinf(fmaf(sc.wf, t2, sc.wp));

      // op4 warp coords; p clamped to [-1,1] => px in [0,4999] exactly
      float posb = fmaf(tf, D_BASE, -1.0f);
      float p = fmaf(sc.amp4, sin4, posb);
      p = fminf(1.0f, fmaxf(-1.0f, p));
      float px = fmaf(p, 2499.5f, 2499.5f);
      int i0 = (int)px;               // trunc == floor (px >= 0)
      int i1 = i0 + 1;
      if (i1 > NTT - 1) i1 = NTT - 1;
      float fr = px - (float)i0;

      // op5 index
      int rt = t - sc.shift;
      if (rt < 0) rt += NTT;

      float xv = rin[t];
      float xl = rin[i0];
      float xr = rin[i1];
      float xs = rin[rt];

      // op0 gaussian noise: bits = o0^o1 -> uniform(NLO,1) -> sqrt2*erfinv
      u32 o0, o1;
      tf2(sc.nk0, sc.nk1, 0u, (u32)(rowbase + t), o0, o1);
      float f = u01(o0 ^ o1);
      float un = fmaxf(NLO, fmaf(f, 2.0f, NLO));
      float nrm = SQRT2 * erfinv_fast(un);

      // mask (unsigned-compare trick; mlen==0 -> never masked)
      float cc = ((u32)(t - (int)mstart) < mlen) ? cc_m : cc_u;

      float y4 = fmaf(xr, fr, xl * (1.0f - fr));
      float r = xv * cc;
      r = fmaf(A0, nrm, r);
      r = fmaf(A3, sin3, r);
      r = fmaf(W4, y4, r);
      r = fmaf(W5, xs, r);

      if (s == 0) rowB[t] = r;
      else xout[rowbase + t] = r;
    }
    __syncthreads();
  }
}

extern "C" void kernel_launch(void* const* d_in, const int* in_sizes, int n_in,
                              void* d_out, int out_size, void* d_ws, size_t ws_size,
                              hipStream_t stream) {
  (void)in_sizes; (void)n_in; (void)d_ws; (void)ws_size; (void)out_size;
  const float* x = (const float*)d_in[0];
  const float* logits = (const float*)d_in[1];
  const float* mag_neg = (const float*)d_in[2];
  const float* mag_pos = (const float*)d_in[3];
  const int* labels = (const int*)d_in[4];
  float* out = (float*)d_out;
  hipLaunchKernelGGL(aug_fused, dim3(NB * NC), dim3(BLK), 0, stream,
                     x, logits, mag_neg, mag_pos, labels, out);
}

// Round 5
// 67.497 us; speedup vs baseline: 2.3128x; 1.4947x over previous
//
#include <hip/hip_runtime.h>
#include <stdint.h>

#pragma clang fp contract(off)

#define NB 128
#define NC 12
#define NTT 5000
#define BLK 256

typedef unsigned int u32;

// Canonical Threefry-2x32, 20 rounds (matches JAX / Random123).
__device__ __forceinline__ void tf2(u32 k0, u32 k1, u32 c0, u32 c1, u32& o0, u32& o1) {
  u32 k2 = k0 ^ k1 ^ 0x1BD11BDAu;
  u32 x0 = c0 + k0, x1 = c1 + k1;
#define TFR(r) x0 += x1; x1 = (x1 << (r)) | (x1 >> (32 - (r))); x1 ^= x0;
  TFR(13) TFR(15) TFR(26) TFR(6)
  x0 += k1; x1 += k2 + 1u;
  TFR(17) TFR(29) TFR(16) TFR(24)
  x0 += k2; x1 += k0 + 2u;
  TFR(13) TFR(15) TFR(26) TFR(6)
  x0 += k0; x1 += k1 + 3u;
  TFR(17) TFR(29) TFR(16) TFR(24)
  x0 += k1; x1 += k2 + 4u;
  TFR(13) TFR(15) TFR(26) TFR(6)
  x0 += k2; x1 += k0 + 5u;
#undef TFR
  o0 = x0; o1 = x1;
}

// JAX f32 uniform bit->float: [1,2) - 1. Partitionable 32-bit bits = o0^o1.
__device__ __forceinline__ float u01(u32 bits) {
  return __uint_as_float((bits >> 9) | 0x3F800000u) - 1.0f;
}

// Giles erfinv, hw-log variant (validated rounds 3/4).
__device__ __forceinline__ float erfinv_fast(float x) {
  float xx = x * x;
  float w = -__logf(1.0f - xx);
  float p;
  if (w < 5.0f) {
    w = w - 2.5f;
    p = fmaf(2.81022636e-08f, w, 3.43273939e-07f);
    p = fmaf(p, w, -3.5233877e-06f);
    p = fmaf(p, w, -4.39150654e-06f);
    p = fmaf(p, w, 0.00021858087f);
    p = fmaf(p, w, -0.00125372503f);
    p = fmaf(p, w, -0.00417768164f);
    p = fmaf(p, w, 0.246640727f);
    p = fmaf(p, w, 1.50140941f);
  } else {
    w = __fsqrt_rn(w) - 3.0f;
    p = fmaf(-0.000200214257f, w, 0.000100950558f);
    p = fmaf(p, w, 0.00134934322f);
    p = fmaf(p, w, -0.00367342844f);
    p = fmaf(p, w, 0.00573950773f);
    p = fmaf(p, w, -0.0076224613f);
    p = fmaf(p, w, 0.00943887047f);
    p = fmaf(p, w, 1.00167406f);
    p = fmaf(p, w, 2.83297682f);
  }
  return p * x;
}

struct SSc {
  float w[7];
  float mag0, scale1, mag3, amp4, freq, ph, wf, wp;
  int start, mlen, shift;
  u32 nk0, nk1;
};

__global__ __launch_bounds__(BLK, 8) void aug_fused(
    const float* __restrict__ xin, const float* __restrict__ logits,
    const float* __restrict__ mag_neg, const float* __restrict__ mag_pos,
    const int* __restrict__ labels, float* __restrict__ xout) {
  __shared__ float rowB[NTT];
  __shared__ SSc ssc[2];

  const int bc = blockIdx.x;
  const int b = bc / NC;
  const int rowbase = bc * NTT;
  const int tid = threadIdx.x;

  // ---- Parallel scalar setup on wave 0: lane L<14 owns (stage s, op j). ----
  if (tid < 64) {
    // Label dtype probe via ballot: int64 labels => all odd 32-bit words zero.
    bool nz = labels[2 * tid + 1] != 0;
    unsigned long long mk = __ballot(nz);
    const int mode64 = (mk == 0ULL) ? 1 : 0;
    const int L = tid;
    if (L < 14) {
      const int s = (L >= 7) ? 1 : 0;
      const int j = L - 7 * s;
      const int lab = mode64 ? labels[2 * b] : labels[b];
      const float lf = (float)lab;

      u32 kk0, kk1, kj0, kj1, k00, k01, o0, o1;
      tf2(0u, 42u, 0u, (u32)s, kk0, kk1);        // fold_in(key(42), s)
      tf2(kk0, kk1, 0u, (u32)j, kj0, kj1);       // own split key ks[j]
      tf2(kk0, kk1, 0u, 0u, k00, k01);           // ks[0] (gumbel key)
      tf2(k00, k01, 0u, (u32)j, o0, o1);         // gumbel bits, counter j
      float u = fmaxf(u01(o0 ^ o1), 1e-20f);
      float g = -__logf(-__logf(u));
      float v = logits[s * 7 + j] + g;

      // softmax over own group of 7 via shuffles (max exact; sum continuous)
      float vk[7];
#pragma unroll
      for (int k = 0; k < 7; ++k) vk[k] = __shfl(v, 7 * s + k);
      float m = vk[0];
#pragma unroll
      for (int k = 1; k < 7; ++k) m = fmaxf(m, vk[k]);
      float sum = 0.0f;
#pragma unroll
      for (int k = 0; k < 7; ++k) sum += __expf(vk[k] - m);
      ssc[s].w[j] = __expf(v - m) / sum;

      // magnitude |mag_neg + lf*(mag_pos - mag_neg)| (exact op order)
      float mn = mag_neg[s * 7 + j];
      float mp = mag_pos[s * 7 + j];
      float d = mp - mn;
      float pr = lf * d;
      float mgj = fabsf(mn + pr);

      if (j == 0) {
        ssc[s].mag0 = mgj;
      } else if (j == 1) {
        ssc[s].scale1 = 1.0f + mgj;
        ssc[s].nk0 = kj0; ssc[s].nk1 = kj1;      // noise key ks[1]
      } else if (j == 2) {
        int ml = (int)floorf(mgj * 5000.0f);     // exact discrete sequence
        ml = ml < 0 ? 0 : (ml > NTT ? NTT : ml);
        tf2(kj0, kj1, 0u, (u32)b, o0, o1);
        int tml = NTT - ml + 1;
        if (tml < 1) tml = 1;
        int st = (int)floorf(u01(o0 ^ o1) * (float)tml);
        ssc[s].start = st; ssc[s].mlen = ml;
      } else if (j == 3) {
        ssc[s].mag3 = mgj;
        tf2(kj0, kj1, 0u, (u32)b, o0, o1);
        float f = u01(o0 ^ o1); float fp = f * 0.3f; ssc[s].freq = fp + 0.05f;
      } else if (j == 4) {
        ssc[s].amp4 = 0.1f * mgj;
        tf2(kj0, kj1, 0u, (u32)b, o0, o1);
        ssc[s].ph = u01(o0 ^ o1) * 6.283185307179586f;
      } else if (j == 5) {
        ssc[s].shift = (int)floorf(mgj * 5000.0f);
        tf2(kj0, kj1, 0u, (u32)b, o0, o1);
        float f = u01(o0 ^ o1); float fp = f * 2.0f; ssc[s].wf = fp + 1.0f;
      } else { // j == 6
        tf2(kj0, kj1, 0u, (u32)b, o0, o1);
        ssc[s].wp = u01(o0 ^ o1) * 6.283185307179586f;
      }
    }
  }
  __syncthreads();

  const float D_T2PI = 6.283185307179586f / 4999.0f;
  const float D_BASE = 2.0f / 4999.0f;
  const float NLO = -0.9999999403953552f;  // nextafter(-1f, 0)
  const float SQRT2 = 1.4142135623730951f;

  // ---- stage 0: read x row from GLOBAL (L1-resident), write rowB (LDS) ----
  {
    const SSc sc = ssc[0];
    const float cc_m = ((sc.w[0] + sc.w[1] * sc.scale1) + sc.w[3]) + sc.w[6];
    const float cc_u = cc_m + sc.w[2];
    const float A0 = sc.w[0] * sc.mag0;
    const float A3 = sc.w[3] * sc.mag3;
    const float W4 = sc.w[4], W5 = sc.w[5];
    const u32 mstart = (u32)sc.start, mlen = (u32)sc.mlen;
    const float* __restrict__ rx = xin + rowbase;

    for (int t = tid; t < NTT; t += BLK) {
      float tf = (float)t;
      float t2 = tf * D_T2PI;
      float sin3 = __sinf(fmaf(sc.freq, t2, sc.ph));
      float sin4 = __sinf(fmaf(sc.wf, t2, sc.wp));

      float posb = fmaf(tf, D_BASE, -1.0f);
      float p = fmaf(sc.amp4, sin4, posb);
      p = fminf(1.0f, fmaxf(-1.0f, p));
      float px = fmaf(p, 2499.5f, 2499.5f);
      int i0 = (int)px;
      int i1 = i0 + 1;
      if (i1 > NTT - 1) i1 = NTT - 1;
      float fr = px - (float)i0;

      int rt = t - sc.shift;
      if (rt < 0) rt += NTT;

      float xv = rx[t];
      float xl = rx[i0];
      float xr = rx[i1];
      float xs = rx[rt];

      u32 o0, o1;
      tf2(sc.nk0, sc.nk1, 0u, (u32)(rowbase + t), o0, o1);
      float f = u01(o0 ^ o1);
      float un = fmaxf(NLO, fmaf(f, 2.0f, NLO));
      float nrm = SQRT2 * erfinv_fast(un);

      float cc = ((u32)(t - (int)mstart) < mlen) ? cc_m : cc_u;

      float y4 = fmaf(xr, fr, xl * (1.0f - fr));
      float r = xv * cc;
      r = fmaf(A0, nrm, r);
      r = fmaf(A3, sin3, r);
      r = fmaf(W4, y4, r);
      r = fmaf(W5, xs, r);

      rowB[t] = r;
    }
  }
  __syncthreads();

  // ---- stage 1: read rowB (LDS), write output row (global, coalesced) ----
  {
    const SSc sc = ssc[1];
    const float cc_m = ((sc.w[0] + sc.w[1] * sc.scale1) + sc.w[3]) + sc.w[6];
    const float cc_u = cc_m + sc.w[2];
    const float A0 = sc.w[0] * sc.mag0;
    const float A3 = sc.w[3] * sc.mag3;
    const float W4 = sc.w[4], W5 = sc.w[5];
    const u32 mstart = (u32)sc.start, mlen = (u32)sc.mlen;

    for (int t = tid; t < NTT; t += BLK) {
      float tf = (float)t;
      float t2 = tf * D_T2PI;
      float sin3 = __sinf(fmaf(sc.freq, t2, sc.ph));
      float sin4 = __sinf(fmaf(sc.wf, t2, sc.wp));

      float posb = fmaf(tf, D_BASE, -1.0f);
      float p = fmaf(sc.amp4, sin4, posb);
      p = fminf(1.0f, fmaxf(-1.0f, p));
      float px = fmaf(p, 2499.5f, 2499.5f);
      int i0 = (int)px;
      int i1 = i0 + 1;
      if (i1 > NTT - 1) i1 = NTT - 1;
      float fr = px - (float)i0;

      int rt = t - sc.shift;
      if (rt < 0) rt += NTT;

      float xv = rowB[t];
      float xl = rowB[i0];
      float xr = rowB[i1];
      float xs = rowB[rt];

      u32 o0, o1;
      tf2(sc.nk0, sc.nk1, 0u, (u32)(rowbase + t), o0, o1);
      float f = u01(o0 ^ o1);
      float un = fmaxf(NLO, fmaf(f, 2.0f, NLO));
      float nrm = SQRT2 * erfinv_fast(un);

      float cc = ((u32)(t - (int)mstart) < mlen) ? cc_m : cc_u;

      float y4 = fmaf(xr, fr, xl * (1.0f - fr));
      float r = xv * cc;
      r = fmaf(A0, nrm, r);
      r = fmaf(A3, sin3, r);
      r = fmaf(W4, y4, r);
      r = fmaf(W5, xs, r);

      xout[rowbase + t] = r;
    }
  }
}

extern "C" void kernel_launch(void* const* d_in, const int* in_sizes, int n_in,
                              void* d_out, int out_size, void* d_ws, size_t ws_size,
                              hipStream_t stream) {
  (void)in_sizes; (void)n_in; (void)d_ws; (void)ws_size; (void)out_size;
  const float* x = (const float*)d_in[0];
  const float* logits = (const float*)d_in[1];
  const float* mag_neg = (const float*)d_in[2];
  const float* mag_pos = (const float*)d_in[3];
  const int* labels = (const int*)d_in[4];
  float* out = (float*)d_out;
  hipLaunchKernelGGL(aug_fused, dim3(NB * NC), dim3(BLK), 0, stream,
                     x, logits, mag_neg, mag_pos, labels, out);
}

// Round 6
// 65.635 us; speedup vs baseline: 2.3784x; 1.0284x over previous
//
#include <hip/hip_runtime.h>
#include <stdint.h>

#pragma clang fp contract(off)

#define NB 128
#define NC 12
#define NTT 5000
#define BLK 256

typedef unsigned int u32;

// Canonical Threefry-2x32, 20 rounds (matches JAX / Random123).
__device__ __forceinline__ void tf2(u32 k0, u32 k1, u32 c0, u32 c1, u32& o0, u32& o1) {
  u32 k2 = k0 ^ k1 ^ 0x1BD11BDAu;
  u32 x0 = c0 + k0, x1 = c1 + k1;
#define TFR(r) x0 += x1; x1 = (x1 << (r)) | (x1 >> (32 - (r))); x1 ^= x0;
  TFR(13) TFR(15) TFR(26) TFR(6)
  x0 += k1; x1 += k2 + 1u;
  TFR(17) TFR(29) TFR(16) TFR(24)
  x0 += k2; x1 += k0 + 2u;
  TFR(13) TFR(15) TFR(26) TFR(6)
  x0 += k0; x1 += k1 + 3u;
  TFR(17) TFR(29) TFR(16) TFR(24)
  x0 += k1; x1 += k2 + 4u;
  TFR(13) TFR(15) TFR(26) TFR(6)
  x0 += k2; x1 += k0 + 5u;
#undef TFR
  o0 = x0; o1 = x1;
}

// JAX f32 uniform bit->float: [1,2) - 1. Partitionable 32-bit bits = o0^o1.
__device__ __forceinline__ float u01(u32 bits) {
  return __uint_as_float((bits >> 9) | 0x3F800000u) - 1.0f;
}

// Giles erfinv core (returns p; caller multiplies by x). hw-log variant,
// validated rounds 3-5.
__device__ __forceinline__ float erfinv_poly(float xx) {
  float w = -__logf(1.0f - xx);
  float p;
  if (w < 5.0f) {
    w = w - 2.5f;
    p = fmaf(2.81022636e-08f, w, 3.43273939e-07f);
    p = fmaf(p, w, -3.5233877e-06f);
    p = fmaf(p, w, -4.39150654e-06f);
    p = fmaf(p, w, 0.00021858087f);
    p = fmaf(p, w, -0.00125372503f);
    p = fmaf(p, w, -0.00417768164f);
    p = fmaf(p, w, 0.246640727f);
    p = fmaf(p, w, 1.50140941f);
  } else {
    w = __fsqrt_rn(w) - 3.0f;
    p = fmaf(-0.000200214257f, w, 0.000100950558f);
    p = fmaf(p, w, 0.00134934322f);
    p = fmaf(p, w, -0.00367342844f);
    p = fmaf(p, w, 0.00573950773f);
    p = fmaf(p, w, -0.0076224613f);
    p = fmaf(p, w, 0.00943887047f);
    p = fmaf(p, w, 1.00167406f);
    p = fmaf(p, w, 2.83297682f);
  }
  return p;
}

struct SSc {
  float w[7];
  float mag0, scale1, mag3, amp4, freq, ph, wf, wp;
  int start, mlen, shift;
  u32 nk0, nk1;
};

__global__ __launch_bounds__(BLK, 6) void aug_fused(
    const float* __restrict__ xin, const float* __restrict__ logits,
    const float* __restrict__ mag_neg, const float* __restrict__ mag_pos,
    const int* __restrict__ labels, float* __restrict__ xout) {
  __shared__ float rowB[NTT];
  __shared__ SSc ssc[2];

  const int bc = blockIdx.x;
  const int b = bc / NC;
  const int rowbase = bc * NTT;
  const int tid = threadIdx.x;

  // ---- Parallel scalar setup on wave 0: lane L<14 owns (stage s, op j). ----
  if (tid < 64) {
    // Label dtype probe via ballot: int64 labels => all odd 32-bit words zero.
    bool nz = labels[2 * tid + 1] != 0;
    unsigned long long mk = __ballot(nz);
    const int mode64 = (mk == 0ULL) ? 1 : 0;
    const int L = tid;
    if (L < 14) {
      const int s = (L >= 7) ? 1 : 0;
      const int j = L - 7 * s;
      const int lab = mode64 ? labels[2 * b] : labels[b];
      const float lf = (float)lab;

      u32 kk0, kk1, kj0, kj1, k00, k01, o0, o1;
      tf2(0u, 42u, 0u, (u32)s, kk0, kk1);        // fold_in(key(42), s)
      tf2(kk0, kk1, 0u, (u32)j, kj0, kj1);       // own split key ks[j]
      tf2(kk0, kk1, 0u, 0u, k00, k01);           // ks[0] (gumbel key)
      tf2(k00, k01, 0u, (u32)j, o0, o1);         // gumbel bits, counter j
      float u = fmaxf(u01(o0 ^ o1), 1e-20f);
      float g = -__logf(-__logf(u));
      float v = logits[s * 7 + j] + g;

      // softmax over own group of 7 via shuffles (max exact; sum continuous)
      float vk[7];
#pragma unroll
      for (int k = 0; k < 7; ++k) vk[k] = __shfl(v, 7 * s + k);
      float m = vk[0];
#pragma unroll
      for (int k = 1; k < 7; ++k) m = fmaxf(m, vk[k]);
      float sum = 0.0f;
#pragma unroll
      for (int k = 0; k < 7; ++k) sum += __expf(vk[k] - m);
      ssc[s].w[j] = __expf(v - m) / sum;

      // magnitude |mag_neg + lf*(mag_pos - mag_neg)| (exact op order)
      float mn = mag_neg[s * 7 + j];
      float mp = mag_pos[s * 7 + j];
      float d = mp - mn;
      float pr = lf * d;
      float mgj = fabsf(mn + pr);

      if (j == 0) {
        ssc[s].mag0 = mgj;
      } else if (j == 1) {
        ssc[s].scale1 = 1.0f + mgj;
        ssc[s].nk0 = kj0; ssc[s].nk1 = kj1;      // noise key ks[1]
      } else if (j == 2) {
        int ml = (int)floorf(mgj * 5000.0f);     // exact discrete sequence
        ml = ml < 0 ? 0 : (ml > NTT ? NTT : ml);
        tf2(kj0, kj1, 0u, (u32)b, o0, o1);
        int tml = NTT - ml + 1;
        if (tml < 1) tml = 1;
        int st = (int)floorf(u01(o0 ^ o1) * (float)tml);
        ssc[s].start = st; ssc[s].mlen = ml;
      } else if (j == 3) {
        ssc[s].mag3 = mgj;
        tf2(kj0, kj1, 0u, (u32)b, o0, o1);
        float f = u01(o0 ^ o1); float fp = f * 0.3f; ssc[s].freq = fp + 0.05f;
      } else if (j == 4) {
        ssc[s].amp4 = 0.1f * mgj;
        tf2(kj0, kj1, 0u, (u32)b, o0, o1);
        ssc[s].ph = u01(o0 ^ o1) * 6.283185307179586f;
      } else if (j == 5) {
        ssc[s].shift = (int)floorf(mgj * 5000.0f);
        tf2(kj0, kj1, 0u, (u32)b, o0, o1);
        float f = u01(o0 ^ o1); float fp = f * 2.0f; ssc[s].wf = fp + 1.0f;
      } else { // j == 6
        tf2(kj0, kj1, 0u, (u32)b, o0, o1);
        ssc[s].wp = u01(o0 ^ o1) * 6.283185307179586f;
      }
    }
  }
  __syncthreads();

  const float D_T2PI = 6.283185307179586f / 4999.0f;
  const float D_BASE = 2.0f / 4999.0f;
  const float NLO = -0.9999999403953552f;  // nextafter(-1f, 0)
  const float SQRT2 = 1.4142135623730951f;

  // ---- stage 0: read x row from GLOBAL (L1-resident), write rowB (LDS) ----
  {
    const SSc sc = ssc[0];
    const float cc_m = ((sc.w[0] + sc.w[1] * sc.scale1) + sc.w[3]) + sc.w[6];
    const float cc_u = cc_m + sc.w[2];
    const float A0s = (sc.w[0] * sc.mag0) * SQRT2;
    const float A3 = sc.w[3] * sc.mag3;
    const float W4 = sc.w[4], W5 = sc.w[5];
    const float fD3 = sc.freq * D_T2PI;   // fold t2 mul into per-sin coeff
    const float fD4 = sc.wf * D_T2PI;
    const u32 mstart = (u32)sc.start, mlen = (u32)sc.mlen;
    const u32 nk0 = sc.nk0, nk1 = sc.nk1;
    const float* __restrict__ rx = xin + rowbase;

#pragma unroll 4
    for (int t = tid; t < NTT; t += BLK) {
      float tf = (float)t;
      float sin3 = __sinf(fmaf(tf, fD3, sc.ph));
      float sin4 = __sinf(fmaf(tf, fD4, sc.wp));

      float posb = fmaf(tf, D_BASE, -1.0f);
      float p = fmaf(sc.amp4, sin4, posb);
      p = fminf(1.0f, fmaxf(-1.0f, p));
      float px = fmaf(p, 2499.5f, 2499.5f);
      int i0 = (int)px;
      int i1 = min(i0 + 1, NTT - 1);
      float fr = px - (float)i0;

      int rt = t - sc.shift;
      if (rt < 0) rt += NTT;

      float xv = rx[t];
      float xl = rx[i0];
      float xr = rx[i1];
      float xs = rx[rt];

      u32 o0, o1;
      tf2(nk0, nk1, 0u, (u32)(rowbase + t), o0, o1);
      float f = u01(o0 ^ o1);
      float un = fmaf(f, 2.0f, NLO);   // >= NLO always: fmax removed (exact)
      float ei = erfinv_poly(un * un) * un;

      float cc = ((u32)(t - (int)mstart) < mlen) ? cc_m : cc_u;

      float y4 = fmaf(xr - xl, fr, xl);
      float r = xv * cc;
      r = fmaf(A0s, ei, r);
      r = fmaf(A3, sin3, r);
      r = fmaf(W4, y4, r);
      r = fmaf(W5, xs, r);

      rowB[t] = r;
    }
  }
  __syncthreads();

  // ---- stage 1: read rowB (LDS), write output row (global, coalesced) ----
  {
    const SSc sc = ssc[1];
    const float cc_m = ((sc.w[0] + sc.w[1] * sc.scale1) + sc.w[3]) + sc.w[6];
    const float cc_u = cc_m + sc.w[2];
    const float A0s = (sc.w[0] * sc.mag0) * SQRT2;
    const float A3 = sc.w[3] * sc.mag3;
    const float W4 = sc.w[4], W5 = sc.w[5];
    const float fD3 = sc.freq * D_T2PI;
    const float fD4 = sc.wf * D_T2PI;
    const u32 mstart = (u32)sc.start, mlen = (u32)sc.mlen;
    const u32 nk0 = sc.nk0, nk1 = sc.nk1;

#pragma unroll 4
    for (int t = tid; t < NTT; t += BLK) {
      float tf = (float)t;
      float sin3 = __sinf(fmaf(tf, fD3, sc.ph));
      float sin4 = __sinf(fmaf(tf, fD4, sc.wp));

      float posb = fmaf(tf, D_BASE, -1.0f);
      float p = fmaf(sc.amp4, sin4, posb);
      p = fminf(1.0f, fmaxf(-1.0f, p));
      float px = fmaf(p, 2499.5f, 2499.5f);
      int i0 = (int)px;
      int i1 = min(i0 + 1, NTT - 1);
      float fr = px - (float)i0;

      int rt = t - sc.shift;
      if (rt < 0) rt += NTT;

      float xv = rowB[t];
      float xl = rowB[i0];
      float xr = rowB[i1];
      float xs = rowB[rt];

      u32 o0, o1;
      tf2(nk0, nk1, 0u, (u32)(rowbase + t), o0, o1);
      float f = u01(o0 ^ o1);
      float un = fmaf(f, 2.0f, NLO);
      float ei = erfinv_poly(un * un) * un;

      float cc = ((u32)(t - (int)mstart) < mlen) ? cc_m : cc_u;

      float y4 = fmaf(xr - xl, fr, xl);
      float r = xv * cc;
      r = fmaf(A0s, ei, r);
      r = fmaf(A3, sin3, r);
      r = fmaf(W4, y4, r);
      r = fmaf(W5, xs, r);

      xout[rowbase + t] = r;
    }
  }
}

extern "C" void kernel_launch(void* const* d_in, const int* in_sizes, int n_in,
                              void* d_out, int out_size, void* d_ws, size_t ws_size,
                              hipStream_t stream) {
  (void)in_sizes; (void)n_in; (void)d_ws; (void)ws_size; (void)out_size;
  const float* x = (const float*)d_in[0];
  const float* logits = (const float*)d_in[1];
  const float* mag_neg = (const float*)d_in[2];
  const float* mag_pos = (const float*)d_in[3];
  const int* labels = (const int*)d_in[4];
  float* out = (float*)d_out;
  hipLaunchKernelGGL(aug_fused, dim3(NB * NC), dim3(BLK), 0, stream,
                     x, logits, mag_neg, mag_pos, labels, out);
}